// Round 13
// baseline (178.880 us; speedup 1.0000x reference)
//
#include <hip/hip_runtime.h>

// QRNN forget-mult: h_t = i_t*z_t + f_t*h_{t-1}, T=4096, B=32, H=256, fp32.
// Round 13: R11 structure (passing, 178us) + pin-asm deep-MLP test.
// R6/R8's U=8 "batches" came back VGPR=64-68: the compiler re-serialized the
// loads into <=4-load groups with its own waitcnts. R12's hand-rolled vmcnt
// rotation was corrupt (codegen hazard). This round: empty pin-asm
// (asm volatile("" : "+v"(x)...)) after 24 loads forces ALL of them issued
// and resident before one compiler-inserted wait -> true 12KB/wave in
// flight, compiler-managed correctness. VGPR counter is the residency proof.

constexpr int T   = 4096;
constexpr int CHN = 32 * 256;   // 8192 channels (B*H)
constexpr int C4  = CHN / 4;    // 2048 float4-channels

typedef float v4f __attribute__((ext_vector_type(4)));

// bid in [0, NC*8): XCD banding — XCD x owns chunks [x*NC/8, (x+1)*NC/8).
template <int NC>
__device__ __forceinline__ void tile_map(int bid, int& chunk, int& col) {
  constexpr int CPX = NC / 8;
  const int xcd = bid & 7;
  const int m   = bid >> 3;
  chunk = xcd * CPX + (m % CPX);
  col   = m / CPX;
}

// ---------------- kernel 1: per-chunk local recurrence + forget product ----------------
template <int NC>
__global__ __launch_bounds__(256, 4) void qrnn_partial(
    const v4f* __restrict__ f, const v4f* __restrict__ z,
    const v4f* __restrict__ ig,
    v4f* __restrict__ Ps, v4f* __restrict__ Hs) {
  constexpr int CL = T / NC;
  constexpr int U  = 8;
  static_assert(CL % U == 0, "");
  int chunk, col;
  tile_map<NC>(blockIdx.x, chunk, col);
  const int c4 = col * 256 + (int)threadIdx.x;
  int idx = chunk * CL * C4 + c4;
  v4f h = {0.f, 0.f, 0.f, 0.f};
  v4f P = {1.f, 1.f, 1.f, 1.f};
  for (int t0 = 0; t0 < CL; t0 += U) {
    v4f rf[U], rz[U], ri[U];
#pragma unroll
    for (int u = 0; u < U; ++u) rf[u] = f[idx + u * C4];
#pragma unroll
    for (int u = 0; u < U; ++u) rz[u] = z[idx + u * C4];
#pragma unroll
    for (int u = 0; u < U; ++u) ri[u] = ig[idx + u * C4];
    // Pin: all 24 loads must be issued & values resident here (one wait),
    // so the compiler cannot re-serialize into small load groups.
    asm volatile(""
        : "+v"(rf[0]), "+v"(rf[1]), "+v"(rf[2]), "+v"(rf[3]),
          "+v"(rf[4]), "+v"(rf[5]), "+v"(rf[6]), "+v"(rf[7]),
          "+v"(rz[0]), "+v"(rz[1]), "+v"(rz[2]), "+v"(rz[3]),
          "+v"(rz[4]), "+v"(rz[5]), "+v"(rz[6]), "+v"(rz[7]),
          "+v"(ri[0]), "+v"(ri[1]), "+v"(ri[2]), "+v"(ri[3]),
          "+v"(ri[4]), "+v"(ri[5]), "+v"(ri[6]), "+v"(ri[7]));
#pragma unroll
    for (int u = 0; u < U; ++u) {
      h = rf[u] * h + ri[u] * rz[u];
      P *= rf[u];
    }
    idx += U * C4;
  }
  Ps[chunk * C4 + c4] = P;
  Hs[chunk * C4 + c4] = h;
}

// ---------------- kernel 2: sequential scan over chunk summaries ----------------
// After this: Hs[k] = hidden state ENTERING chunk k.
template <int NC>
__global__ __launch_bounds__(256) void qrnn_scan(
    const v4f* __restrict__ hinit,
    const v4f* __restrict__ Ps, v4f* __restrict__ Hs) {
  const int c4 = blockIdx.x * 256 + threadIdx.x;
  v4f carry = hinit[c4];
  constexpr int US = 16;
  static_assert(NC % US == 0, "");
  for (int k0 = 0; k0 < NC; k0 += US) {
    v4f rp[US], rh[US];
#pragma unroll
    for (int u = 0; u < US; ++u) rp[u] = Ps[(k0 + u) * C4 + c4];
#pragma unroll
    for (int u = 0; u < US; ++u) rh[u] = Hs[(k0 + u) * C4 + c4];
#pragma unroll
    for (int u = 0; u < US; ++u) {
      Hs[(k0 + u) * C4 + c4] = carry;
      carry = rp[u] * carry + rh[u];
    }
  }
}

// ---------------- kernel 3: recompute chunk from exact carry, write output ----------------
template <int NC>
__global__ __launch_bounds__(256, 4) void qrnn_final(
    const v4f* __restrict__ f, const v4f* __restrict__ z,
    const v4f* __restrict__ ig, const v4f* __restrict__ Hs,
    v4f* __restrict__ out) {
  constexpr int CL = T / NC;
  constexpr int U  = 4;
  static_assert(CL % U == 0, "");
  int chunk, col;
  tile_map<NC>(blockIdx.x, chunk, col);
  const int c4 = col * 256 + (int)threadIdx.x;
  int idx = chunk * CL * C4 + c4;
  v4f h = Hs[chunk * C4 + c4];
  for (int t0 = 0; t0 < CL; t0 += U) {
    v4f rf[U], rz[U], ri[U];
#pragma unroll
    for (int u = 0; u < U; ++u) rf[u] = f[idx + u * C4];
#pragma unroll
    for (int u = 0; u < U; ++u) rz[u] = z[idx + u * C4];
#pragma unroll
    for (int u = 0; u < U; ++u) ri[u] = ig[idx + u * C4];
    asm volatile(""
        : "+v"(rf[0]), "+v"(rf[1]), "+v"(rf[2]), "+v"(rf[3]),
          "+v"(rz[0]), "+v"(rz[1]), "+v"(rz[2]), "+v"(rz[3]),
          "+v"(ri[0]), "+v"(ri[1]), "+v"(ri[2]), "+v"(ri[3]));
#pragma unroll
    for (int u = 0; u < U; ++u) {
      h = rf[u] * h + ri[u] * rz[u];
      __builtin_nontemporal_store(h, out + idx + u * C4);  // out never re-read
    }
    idx += U * C4;
  }
}

template <int NC>
static void launch_all(const v4f* f, const v4f* z, const v4f* ig,
                       const v4f* hinit, v4f* out, void* ws,
                       hipStream_t stream) {
  v4f* Ps = (v4f*)ws;
  v4f* Hs = (v4f*)((char*)ws + (size_t)NC * CHN * sizeof(float));
  qrnn_partial<NC><<<dim3(NC * 8), dim3(256), 0, stream>>>(f, z, ig, Ps, Hs);
  qrnn_scan<NC><<<dim3(C4 / 256), dim3(256), 0, stream>>>(hinit, Ps, Hs);
  qrnn_final<NC><<<dim3(NC * 8), dim3(256), 0, stream>>>(f, z, ig, Hs, out);
}

extern "C" void kernel_launch(void* const* d_in, const int* in_sizes, int n_in,
                              void* d_out, int out_size, void* d_ws, size_t ws_size,
                              hipStream_t stream) {
  const v4f* f     = (const v4f*)d_in[0];
  const v4f* z     = (const v4f*)d_in[1];
  const v4f* ig    = (const v4f*)d_in[2];
  const v4f* hinit = (const v4f*)d_in[3];
  v4f* out = (v4f*)d_out;

  auto need = [](int nc) { return 2ull * nc * CHN * sizeof(float); };
  if (ws_size >= need(64)) {
    launch_all<64>(f, z, ig, hinit, out, d_ws, stream);   // 4 MiB ws
  } else {
    launch_all<16>(f, z, ig, hinit, out, d_ws, stream);   // 1 MiB ws
  }
}